// Round 1
// baseline (369.573 us; speedup 1.0000x reference)
//
#include <hip/hip_runtime.h>
#include <hip/hip_bf16.h>
#include <cstdint>

#define TSEQ 4096
#define CDIM 2048
#define HDIM 128
#define NCOL 384   // 3*H, qkv packed per row: [q(128) | k(128) | v(128)]

typedef short bf8v __attribute__((ext_vector_type(8)));  // 8 bf16 raw bits (4 VGPRs)
typedef float f4v  __attribute__((ext_vector_type(4)));

__device__ __forceinline__ unsigned short f2b(float f) {
  union { float f; unsigned u; } v; v.f = f;
  unsigned u = v.u;
  return (unsigned short)((u + 0x7fffu + ((u >> 16) & 1u)) >> 16);  // RNE
}

__device__ __forceinline__ f4v mfma16(bf8v a, bf8v b, f4v c) {
  return __builtin_amdgcn_mfma_f32_16x16x32_bf16(a, b, c, 0, 0, 0);
}

// ---------------- Kernel 1: Wq|Wk|Wv fp32 -> Wcat bf16 [384][2048] ----------------
__global__ void wcat_kernel(const float* __restrict__ Wq, const float* __restrict__ Wk,
                            const float* __restrict__ Wv, unsigned short* __restrict__ Wcat) {
  int e = (blockIdx.x * 256 + threadIdx.x) * 4;
  int n = e >> 11;          // row in [0,384)
  int k = e & 2047;
  const float* src;
  if (n < 128)      src = Wq + (size_t)n * CDIM + k;
  else if (n < 256) src = Wk + (size_t)(n - 128) * CDIM + k;
  else              src = Wv + (size_t)(n - 256) * CDIM + k;
  float4 f = *(const float4*)src;
  ushort4 o;
  o.x = f2b(f.x); o.y = f2b(f.y); o.z = f2b(f.z); o.w = f2b(f.w);
  *(ushort4*)(Wcat + e) = o;
}

// ---------------- Kernel 2: qkv = idx @ Wcat^T  (bf16 MFMA, 128x128 tile) ----------------
// A: idx fp32 [16384][2048] (converted to bf16 during LDS staging)
// B: Wcat bf16 [384][2048]  (B^T layout -> same frag load as A)
// C: qkv bf16 [16384][384]
__global__ __launch_bounds__(256, 2) void proj_gemm(const float* __restrict__ A,
                                                    const unsigned short* __restrict__ Bw,
                                                    unsigned short* __restrict__ Cq) {
  __shared__ unsigned short As[128][40];  // [m][k], pad 32->40 (2-way bank alias = free)
  __shared__ unsigned short Bs[128][40];  // [n][k]
  const int m0 = blockIdx.x * 128;
  const int n0 = blockIdx.y * 128;
  const int tid = threadIdx.x;
  const int lane = tid & 63;
  const int w = tid >> 6;
  const int wm = (w & 1) * 64, wn = (w >> 1) * 64;  // 2x2 wave grid, 64x64 per wave
  const int llo = lane & 15, lhi = lane >> 4;

  f4v acc[4][4];
#pragma unroll
  for (int i = 0; i < 4; ++i)
#pragma unroll
    for (int j = 0; j < 4; ++j) acc[i][j] = (f4v){0.f, 0.f, 0.f, 0.f};

  const int ar = tid >> 3, ac = (tid & 7) * 4;  // A stage: 32 rows/pass, float4 each
  const int br = tid >> 2, bc = (tid & 3) * 8;  // B stage: 64 rows/pass, 8 bf16 each

  for (int k0 = 0; k0 < CDIM; k0 += 32) {
#pragma unroll
    for (int p = 0; p < 4; ++p) {
      int row = p * 32 + ar;
      float4 f = *(const float4*)(A + (size_t)(m0 + row) * CDIM + k0 + ac);
      ushort4 o;
      o.x = f2b(f.x); o.y = f2b(f.y); o.z = f2b(f.z); o.w = f2b(f.w);
      *(ushort4*)&As[row][ac] = o;
    }
#pragma unroll
    for (int p = 0; p < 2; ++p) {
      int row = p * 64 + br;
      *(uint4*)&Bs[row][bc] = *(const uint4*)(Bw + (size_t)(n0 + row) * CDIM + k0 + bc);
    }
    __syncthreads();
    bf8v af[4], bfr[4];
#pragma unroll
    for (int i = 0; i < 4; ++i) af[i]  = *(const bf8v*)&As[wm + i * 16 + llo][lhi * 8];
#pragma unroll
    for (int j = 0; j < 4; ++j) bfr[j] = *(const bf8v*)&Bs[wn + j * 16 + llo][lhi * 8];
#pragma unroll
    for (int i = 0; i < 4; ++i)
#pragma unroll
      for (int j = 0; j < 4; ++j) acc[i][j] = mfma16(af[i], bfr[j], acc[i][j]);
    __syncthreads();
  }
  // epilogue: C/D layout col=lane&15, row=(lane>>4)*4+r
#pragma unroll
  for (int i = 0; i < 4; ++i)
#pragma unroll
    for (int j = 0; j < 4; ++j)
#pragma unroll
      for (int r = 0; r < 4; ++r) {
        int row = m0 + wm + i * 16 + lhi * 4 + r;
        int col = n0 + wn + j * 16 + llo;
        Cq[(size_t)row * NCOL + col] = f2b(acc[i][j][r]);
      }
}

// ---------------- Kernel 2b: vT[b][h][t] = qkv[b*T+t][256+h]  (64x64 LDS transpose) ----------------
__global__ void vtrans(const unsigned short* __restrict__ qkv, unsigned short* __restrict__ vT) {
  __shared__ unsigned short tile[64][72];
  const int t0 = blockIdx.x * 64;
  const int h0 = blockIdx.y * 64;
  const int b  = blockIdx.z;
  const int tid = threadIdx.x;
  const int r = tid >> 3, c = (tid & 7) * 8;
#pragma unroll
  for (int p = 0; p < 2; ++p) {
    int row = p * 32 + r;
    *(uint4*)&tile[row][c] =
        *(const uint4*)(qkv + (size_t)(b * TSEQ + t0 + row) * NCOL + 256 + h0 + c);
  }
  __syncthreads();
#pragma unroll
  for (int p = 0; p < 2; ++p) {
    int h = p * 32 + r;
    ushort4 lo, hi;
    lo.x = tile[c + 0][h]; lo.y = tile[c + 1][h]; lo.z = tile[c + 2][h]; lo.w = tile[c + 3][h];
    hi.x = tile[c + 4][h]; hi.y = tile[c + 5][h]; hi.z = tile[c + 6][h]; hi.w = tile[c + 7][h];
    size_t o = (size_t)(b * HDIM + h0 + h) * TSEQ + t0 + c;
    *(ushort4*)(vT + o) = lo;
    *(ushort4*)(vT + o + 4) = hi;
  }
}

// ---------------- Kernel 3: flash attention, S = K.Q^T (roles swapped per reference) ----------------
// block = 256 thr (4 waves), 64 i-rows/block (16 per wave), j-tiles of 64
__global__ __launch_bounds__(256) void attn_kernel(const unsigned short* __restrict__ qkv,
                                                   const unsigned short* __restrict__ vT,
                                                   float* __restrict__ out) {
  __shared__ unsigned short Qs[64][136];   // [j][h]   pad 128->136
  __shared__ unsigned short Vt[128][72];   // [h][j]   pad 64->72
  __shared__ unsigned short Ps[4][16][72]; // per-wave P staging (C/D -> A layout)
  const int it = blockIdx.x, b = blockIdx.y;
  const int i0 = it * 64;
  const int tid = threadIdx.x;
  const int w = tid >> 6, lane = tid & 63;
  const int llo = lane & 15, lhi = lane >> 4;
  const float scale = 0.022097086912079608f;  // 2048^-0.5

  // K strip (this wave's 16 i-rows) kept in registers for the whole loop
  bf8v aK[4];
  {
    const unsigned short* kp = qkv + (size_t)(b * TSEQ + i0 + w * 16 + llo) * NCOL + HDIM;
#pragma unroll
    for (int kk = 0; kk < 4; ++kk) aK[kk] = *(const bf8v*)(kp + kk * 32 + lhi * 8);
  }

  f4v Oacc[8];
#pragma unroll
  for (int nt = 0; nt < 8; ++nt) Oacc[nt] = (f4v){0.f, 0.f, 0.f, 0.f};
  float mrow[4] = {-3.0e38f, -3.0e38f, -3.0e38f, -3.0e38f};
  float lrow[4] = {0.f, 0.f, 0.f, 0.f};

  const int qjl = tid >> 4, qhc = (tid & 15) * 8;
  const int vh  = tid >> 3, vjc = (tid & 7) * 8;

  for (int jt = 0; jt <= it; ++jt) {
    const int j0 = jt * 64;
    __syncthreads();
    // stage Q j-tile [64][128]
#pragma unroll
    for (int p = 0; p < 4; ++p) {
      int row = p * 16 + qjl;
      *(uint4*)&Qs[row][qhc] = *(const uint4*)(qkv + (size_t)(b * TSEQ + j0 + row) * NCOL + qhc);
    }
    // stage V^T j-tile [128][64]
#pragma unroll
    for (int p = 0; p < 4; ++p) {
      int h = p * 32 + vh;
      *(uint4*)&Vt[h][vjc] = *(const uint4*)(vT + (size_t)(b * HDIM + h) * TSEQ + j0 + vjc);
    }
    __syncthreads();

    // S strip 16x64: A=K (regs), B=Q^T from Qs
    f4v S[4];
#pragma unroll
    for (int ct = 0; ct < 4; ++ct) {
      f4v acc = (f4v){0.f, 0.f, 0.f, 0.f};
#pragma unroll
      for (int kk = 0; kk < 4; ++kk) {
        bf8v bq = *(const bf8v*)&Qs[ct * 16 + llo][kk * 32 + lhi * 8];
        acc = mfma16(aK[kk], bq, acc);
      }
      S[ct] = acc * scale;
    }
    // causal mask (only diagonal tile can have j > i)
    if (jt == it) {
#pragma unroll
      for (int ct = 0; ct < 4; ++ct)
#pragma unroll
        for (int r = 0; r < 4; ++r) {
          int j = j0 + ct * 16 + llo;
          int i = i0 + w * 16 + lhi * 4 + r;
          if (j > i) S[ct][r] = -3.0e38f;
        }
    }
    // online softmax, per row r (C/D row mapping = lhi*4+r, same as O acc rows)
    float alpha[4];
#pragma unroll
    for (int r = 0; r < 4; ++r) {
      float tm = fmaxf(fmaxf(S[0][r], S[1][r]), fmaxf(S[2][r], S[3][r]));
#pragma unroll
      for (int off = 1; off < 16; off <<= 1) tm = fmaxf(tm, __shfl_xor(tm, off));
      float mn = fmaxf(mrow[r], tm);
      alpha[r] = __expf(mrow[r] - mn);
      mrow[r] = mn;
      float rs = 0.f;
#pragma unroll
      for (int ct = 0; ct < 4; ++ct) {
        float p = __expf(S[ct][r] - mn);
        S[ct][r] = p;
        rs += p;
      }
#pragma unroll
      for (int off = 1; off < 16; off <<= 1) rs += __shfl_xor(rs, off);
      lrow[r] = lrow[r] * alpha[r] + rs;
    }
    // P: C/D layout -> LDS -> A layout (wave-private, no barrier needed)
#pragma unroll
    for (int ct = 0; ct < 4; ++ct)
#pragma unroll
      for (int r = 0; r < 4; ++r)
        Ps[w][lhi * 4 + r][ct * 16 + llo] = f2b(S[ct][r]);
    bf8v aP[2];
#pragma unroll
    for (int kk = 0; kk < 2; ++kk) aP[kk] = *(const bf8v*)&Ps[w][llo][kk * 32 + lhi * 8];
    // O = O*alpha + P @ V
#pragma unroll
    for (int nt = 0; nt < 8; ++nt) {
      f4v o = Oacc[nt];
#pragma unroll
      for (int r = 0; r < 4; ++r) o[r] *= alpha[r];
#pragma unroll
      for (int kk = 0; kk < 2; ++kk) {
        bf8v bv = *(const bf8v*)&Vt[nt * 16 + llo][kk * 32 + lhi * 8];
        o = mfma16(aP[kk], bv, o);
      }
      Oacc[nt] = o;
    }
  }
  // epilogue: out fp32 [b][i][h]
#pragma unroll
  for (int nt = 0; nt < 8; ++nt)
#pragma unroll
    for (int r = 0; r < 4; ++r) {
      size_t row = (size_t)(b * TSEQ + i0 + w * 16 + lhi * 4 + r);
      out[row * HDIM + nt * 16 + llo] = Oacc[nt][r] / lrow[r];
    }
}

extern "C" void kernel_launch(void* const* d_in, const int* in_sizes, int n_in,
                              void* d_out, int out_size, void* d_ws, size_t ws_size,
                              hipStream_t stream) {
  const float* idx = (const float*)d_in[0];
  const float* Wq  = (const float*)d_in[1];
  const float* Wk  = (const float*)d_in[2];
  const float* Wv  = (const float*)d_in[3];
  float* out = (float*)d_out;
  char* ws = (char*)d_ws;
  unsigned short* Wcat = (unsigned short*)ws;                       // 1.5 MB
  unsigned short* qkv  = (unsigned short*)(ws + (size_t)(2  << 20)); // 12.6 MB
  unsigned short* vT   = (unsigned short*)(ws + (size_t)(16 << 20)); // 4 MB

  wcat_kernel<<<768, 256, 0, stream>>>(Wq, Wk, Wv, Wcat);
  proj_gemm<<<dim3(128, 3), 256, 0, stream>>>(idx, Wcat, qkv);
  vtrans<<<dim3(64, 2, 4), 256, 0, stream>>>(qkv, vT);
  attn_kernel<<<dim3(64, 4), 256, 0, stream>>>(qkv, vT, out);
}

// Round 2
// 345.062 us; speedup vs baseline: 1.0710x; 1.0710x over previous
//
#include <hip/hip_runtime.h>
#include <hip/hip_bf16.h>
#include <cstdint>

#define TSEQ 4096
#define CDIM 2048
#define HDIM 128
#define NCOL 384   // 3*H, qkv packed per row: [q(128) | k(128) | v(128)]

typedef short bf8v __attribute__((ext_vector_type(8)));  // 8 bf16 raw bits (4 VGPRs)
typedef float f4v  __attribute__((ext_vector_type(4)));

__device__ __forceinline__ unsigned short f2b(float f) {
  union { float f; unsigned u; } v; v.f = f;
  unsigned u = v.u;
  return (unsigned short)((u + 0x7fffu + ((u >> 16) & 1u)) >> 16);  // RNE
}

__device__ __forceinline__ f4v mfma16(bf8v a, bf8v b, f4v c) {
  return __builtin_amdgcn_mfma_f32_16x16x32_bf16(a, b, c, 0, 0, 0);
}

// ---------------- Kernel 1: Wq|Wk|Wv fp32 -> Wcat bf16 [384][2048] ----------------
__global__ void wcat_kernel(const float* __restrict__ Wq, const float* __restrict__ Wk,
                            const float* __restrict__ Wv, unsigned short* __restrict__ Wcat) {
  int e = (blockIdx.x * 256 + threadIdx.x) * 4;
  int n = e >> 11;          // row in [0,384)
  int k = e & 2047;
  const float* src;
  if (n < 128)      src = Wq + (size_t)n * CDIM + k;
  else if (n < 256) src = Wk + (size_t)(n - 128) * CDIM + k;
  else              src = Wv + (size_t)(n - 256) * CDIM + k;
  float4 f = *(const float4*)src;
  ushort4 o;
  o.x = f2b(f.x); o.y = f2b(f.y); o.z = f2b(f.z); o.w = f2b(f.w);
  *(ushort4*)(Wcat + e) = o;
}

// ---------------- Kernel 2: qkv = idx @ Wcat^T  (bf16 MFMA, 128x128 tile) ----------------
__global__ __launch_bounds__(256, 2) void proj_gemm(const float* __restrict__ A,
                                                    const unsigned short* __restrict__ Bw,
                                                    unsigned short* __restrict__ Cq) {
  __shared__ unsigned short As[128][40];
  __shared__ unsigned short Bs[128][40];
  const int m0 = blockIdx.x * 128;
  const int n0 = blockIdx.y * 128;
  const int tid = threadIdx.x;
  const int lane = tid & 63;
  const int w = tid >> 6;
  const int wm = (w & 1) * 64, wn = (w >> 1) * 64;
  const int llo = lane & 15, lhi = lane >> 4;

  f4v acc[4][4];
#pragma unroll
  for (int i = 0; i < 4; ++i)
#pragma unroll
    for (int j = 0; j < 4; ++j) acc[i][j] = (f4v){0.f, 0.f, 0.f, 0.f};

  const int ar = tid >> 3, ac = (tid & 7) * 4;
  const int br = tid >> 2, bc = (tid & 3) * 8;

  for (int k0 = 0; k0 < CDIM; k0 += 32) {
#pragma unroll
    for (int p = 0; p < 4; ++p) {
      int row = p * 32 + ar;
      float4 f = *(const float4*)(A + (size_t)(m0 + row) * CDIM + k0 + ac);
      ushort4 o;
      o.x = f2b(f.x); o.y = f2b(f.y); o.z = f2b(f.z); o.w = f2b(f.w);
      *(ushort4*)&As[row][ac] = o;
    }
#pragma unroll
    for (int p = 0; p < 2; ++p) {
      int row = p * 64 + br;
      *(uint4*)&Bs[row][bc] = *(const uint4*)(Bw + (size_t)(n0 + row) * CDIM + k0 + bc);
    }
    __syncthreads();
    bf8v af[4], bfr[4];
#pragma unroll
    for (int i = 0; i < 4; ++i) af[i]  = *(const bf8v*)&As[wm + i * 16 + llo][lhi * 8];
#pragma unroll
    for (int j = 0; j < 4; ++j) bfr[j] = *(const bf8v*)&Bs[wn + j * 16 + llo][lhi * 8];
#pragma unroll
    for (int i = 0; i < 4; ++i)
#pragma unroll
      for (int j = 0; j < 4; ++j) acc[i][j] = mfma16(af[i], bfr[j], acc[i][j]);
    __syncthreads();
  }
#pragma unroll
  for (int i = 0; i < 4; ++i)
#pragma unroll
    for (int j = 0; j < 4; ++j)
#pragma unroll
      for (int r = 0; r < 4; ++r) {
        int row = m0 + wm + i * 16 + lhi * 4 + r;
        int col = n0 + wn + j * 16 + llo;
        Cq[(size_t)row * NCOL + col] = f2b(acc[i][j][r]);
      }
}

// ---------------- Kernel 2b: pack Q (colbase=0) / K (colbase=128) into frag-major ----------------
// dst[((b*256 + tile16)*4 + kk)*64 + lane][8]: lane holds frag elem (m/n = lane&15, k = (lane>>4)*8+e)
__global__ void pack_frags(const unsigned short* __restrict__ qkv,
                           unsigned short* __restrict__ dst, int colbase) {
  int x = blockIdx.x;          // b*256 + tile16
  int b = x >> 8, t16 = x & 255;
  int t = threadIdx.x;
  int kk = t >> 6, lhi = (t >> 4) & 3, llo = t & 15;
  size_t row = (size_t)(b * TSEQ + t16 * 16 + llo);
  bf8v v = *(const bf8v*)(qkv + row * NCOL + colbase + kk * 32 + lhi * 8);
  *(bf8v*)(dst + ((size_t)x * 256 + t) * 8) = v;
}

// ---------------- Kernel 2c: pack V into PV B-frag-major ----------------
// VB[((b*128 + jb32)*8 + ht)*64 + lane][8]: lane holds B[n=h16=lane&15][k=j = (lane>>4)*8+e]
__global__ void pack_vb(const unsigned short* __restrict__ qkv,
                        unsigned short* __restrict__ VB) {
  __shared__ unsigned short tile[64][136];
  int x = blockIdx.x;  // b*64 + j64
  int b = x >> 6, j64 = x & 63;
  int t = threadIdx.x;
  {
    int r = t >> 2, c = (t & 3) * 32;
    const unsigned short* src = qkv + (size_t)(b * TSEQ + j64 * 64 + r) * NCOL + 256 + c;
    *(uint4*)&tile[r][c]      = *(const uint4*)(src);
    *(uint4*)&tile[r][c + 8]  = *(const uint4*)(src + 8);
    *(uint4*)&tile[r][c + 16] = *(const uint4*)(src + 16);
    *(uint4*)&tile[r][c + 24] = *(const uint4*)(src + 24);
  }
  __syncthreads();
#pragma unroll
  for (int p = 0; p < 4; ++p) {
    int ss = p * 256 + t;
    int jb = ss >> 9, ht = (ss >> 6) & 7, lane = ss & 63;
    int llo = lane & 15, lhi = lane >> 4;
    bf8v v;
#pragma unroll
    for (int e = 0; e < 8; ++e) v[e] = (short)tile[jb * 32 + lhi * 8 + e][ht * 16 + llo];
    *(bf8v*)(VB + (((size_t)(b * 128 + j64 * 2 + jb) * 8 + ht) * 64 + lane) * 8) = v;
  }
}

// ---------------- Kernel 3: flash attention v2 ----------------
// 1024 blocks x 256 thr. Block = one 16-row K strip; 4 waves split the jt range
// interleaved (wave w: jt = w, w+4, ...). No barriers in the loop: all MFMA
// operands are coalesced 16B frag loads from the packed buffers. End: LDS merge.
__global__ __launch_bounds__(256, 4) void attn2(const unsigned short* __restrict__ QB,
                                                const unsigned short* __restrict__ KA,
                                                const unsigned short* __restrict__ VB,
                                                float* __restrict__ out) {
  __shared__ union SM {
    unsigned short Ps[4][16][68];                       // wave-private P C/D->A staging
    struct { float Om[4][16][132]; float Mm[4][16]; float Lm[4][16]; } mg;
  } sm;
  const int x = blockIdx.x;
  const int pair = x >> 1, member = x & 1;
  const int b = pair & 3, sp = pair >> 2;
  const int s = member ? (255 - sp) : sp;   // pair long+short strips for CU balance
  const int lastjt = s >> 2;
  const int tid = threadIdx.x;
  const int w = tid >> 6, lane = tid & 63;
  const int llo = lane & 15, lhi = lane >> 4;
  const float scale = 0.022097086912079608f;  // 2048^-0.5

  // K strip A-frags (same 16 rows for all 4 waves)
  bf8v aK[4];
  {
    const unsigned short* kp = KA + (size_t)(b * 256 + s) * 2048;  // 4 kk * 64 lanes * 8
#pragma unroll
    for (int kk = 0; kk < 4; ++kk) aK[kk] = *(const bf8v*)(kp + (kk * 64 + lane) * 8);
  }

  f4v Oacc[8];
#pragma unroll
  for (int nt = 0; nt < 8; ++nt) Oacc[nt] = (f4v){0.f, 0.f, 0.f, 0.f};
  float mrow[4] = {-3.0e38f, -3.0e38f, -3.0e38f, -3.0e38f};
  float lrow[4] = {0.f, 0.f, 0.f, 0.f};

  for (int jt = w; jt <= lastjt; jt += 4) {
    // ---- S = K . Q^T  (16 rows x 64 j), B-frags straight from QB ----
    const unsigned short* qp = QB + (size_t)(b * 256 + jt * 4) * 2048;
    f4v S[4];
#pragma unroll
    for (int ct = 0; ct < 4; ++ct) {
      f4v acc = (f4v){0.f, 0.f, 0.f, 0.f};
#pragma unroll
      for (int kk = 0; kk < 4; ++kk) {
        bf8v bq = *(const bf8v*)(qp + ((ct * 4 + kk) * 64 + lane) * 8);
        acc = mfma16(aK[kk], bq, acc);
      }
      S[ct] = acc * scale;
    }
    // causal mask: only the last tile of the strip can have j > i
    if (jt == lastjt) {
#pragma unroll
      for (int ct = 0; ct < 4; ++ct)
#pragma unroll
        for (int r = 0; r < 4; ++r) {
          int j = jt * 64 + ct * 16 + llo;
          int i = s * 16 + lhi * 4 + r;
          if (j > i) S[ct][r] = -3.0e38f;
        }
    }
    // ---- online softmax (per row r; row's 64 cols live in llo lanes x 4 regs) ----
    float alpha[4];
#pragma unroll
    for (int r = 0; r < 4; ++r) {
      float tm = fmaxf(fmaxf(S[0][r], S[1][r]), fmaxf(S[2][r], S[3][r]));
#pragma unroll
      for (int off = 1; off < 16; off <<= 1) tm = fmaxf(tm, __shfl_xor(tm, off));
      float mn = fmaxf(mrow[r], tm);
      alpha[r] = __expf(mrow[r] - mn);
      mrow[r] = mn;
      float rs = 0.f;
#pragma unroll
      for (int ct = 0; ct < 4; ++ct) {
        float p = __expf(S[ct][r] - mn);
        S[ct][r] = p;
        rs += p;
      }
#pragma unroll
      for (int off = 1; off < 16; off <<= 1) rs += __shfl_xor(rs, off);
      lrow[r] = lrow[r] * alpha[r] + rs;
    }
    // ---- P: C/D layout -> LDS -> A layout (wave-private) ----
#pragma unroll
    for (int ct = 0; ct < 4; ++ct)
#pragma unroll
      for (int r = 0; r < 4; ++r)
        sm.Ps[w][lhi * 4 + r][ct * 16 + llo] = f2b(S[ct][r]);
    bf8v aP[2];
#pragma unroll
    for (int kk = 0; kk < 2; ++kk) aP[kk] = *(const bf8v*)&sm.Ps[w][llo][kk * 32 + lhi * 8];
    // ---- O = O*alpha + P @ V, B-frags straight from VB ----
    const unsigned short* vp = VB + (size_t)(b * 128 + jt * 2) * 4096;  // 2 jb * 8 ht * 512
#pragma unroll
    for (int nt = 0; nt < 8; ++nt) {
      f4v o = Oacc[nt];
#pragma unroll
      for (int r = 0; r < 4; ++r) o[r] *= alpha[r];
#pragma unroll
      for (int kk = 0; kk < 2; ++kk) {
        bf8v bv = *(const bf8v*)(vp + ((kk * 8 + nt) * 64 + lane) * 8);
        o = mfma16(aP[kk], bv, o);
      }
      Oacc[nt] = o;
    }
  }

  // ---- merge the 4 waves' partials (split-softmax combine) ----
  __syncthreads();  // everyone done with Ps; union flips to merge layout
#pragma unroll
  for (int nt = 0; nt < 8; ++nt)
#pragma unroll
    for (int r = 0; r < 4; ++r)
      sm.mg.Om[w][lhi * 4 + r][nt * 16 + llo] = Oacc[nt][r];
  if (llo == 0) {
#pragma unroll
    for (int r = 0; r < 4; ++r) {
      sm.mg.Mm[w][lhi * 4 + r] = mrow[r];
      sm.mg.Lm[w][lhi * 4 + r] = lrow[r];
    }
  }
  __syncthreads();
  {
    int row = tid >> 4, c0 = (tid & 15) * 8;
    float m0 = sm.mg.Mm[0][row], m1 = sm.mg.Mm[1][row];
    float m2 = sm.mg.Mm[2][row], m3 = sm.mg.Mm[3][row];
    float M = fmaxf(fmaxf(m0, m1), fmaxf(m2, m3));
    float e0 = __expf(m0 - M), e1 = __expf(m1 - M);
    float e2 = __expf(m2 - M), e3 = __expf(m3 - M);
    float L = sm.mg.Lm[0][row] * e0 + sm.mg.Lm[1][row] * e1 +
              sm.mg.Lm[2][row] * e2 + sm.mg.Lm[3][row] * e3;
    float inv = 1.0f / L;
    float* op = out + (size_t)(b * TSEQ + s * 16 + row) * HDIM + c0;
#pragma unroll
    for (int e = 0; e < 8; ++e) {
      float o = sm.mg.Om[0][row][c0 + e] * e0 + sm.mg.Om[1][row][c0 + e] * e1 +
                sm.mg.Om[2][row][c0 + e] * e2 + sm.mg.Om[3][row][c0 + e] * e3;
      op[e] = o * inv;
    }
  }
}

extern "C" void kernel_launch(void* const* d_in, const int* in_sizes, int n_in,
                              void* d_out, int out_size, void* d_ws, size_t ws_size,
                              hipStream_t stream) {
  const float* idx = (const float*)d_in[0];
  const float* Wq  = (const float*)d_in[1];
  const float* Wk  = (const float*)d_in[2];
  const float* Wv  = (const float*)d_in[3];
  float* out = (float*)d_out;
  char* ws = (char*)d_ws;
  unsigned short* Wcat = (unsigned short*)ws;                        // 1.57 MB
  unsigned short* qkv  = (unsigned short*)(ws + ((size_t)2  << 20)); // 12.6 MB
  unsigned short* QB   = (unsigned short*)(ws + ((size_t)16 << 20)); // 4.2 MB
  unsigned short* KA   = (unsigned short*)(ws + ((size_t)21 << 20)); // 4.2 MB
  unsigned short* VB   = (unsigned short*)(ws + ((size_t)26 << 20)); // 4.2 MB

  wcat_kernel<<<768, 256, 0, stream>>>(Wq, Wk, Wv, Wcat);
  proj_gemm<<<dim3(128, 3), 256, 0, stream>>>(idx, Wcat, qkv);
  pack_frags<<<1024, 256, 0, stream>>>(qkv, QB, 0);
  pack_frags<<<1024, 256, 0, stream>>>(qkv, KA, 128);
  pack_vb<<<256, 256, 0, stream>>>(qkv, VB);
  attn2<<<1024, 256, 0, stream>>>(QB, KA, VB, out);
}